// Round 11
// baseline (816.456 us; speedup 1.0000x reference)
//
#include <hip/hip_runtime.h>

// EventADModel: 2-frame 2-layer event GRU (H=256) + coord GRU (H=32, 1 step from 0)
// + fused linear fusion head, all via bf16 MFMA GEMMs with fused gate epilogues.
//
// R11: baseline (784us) + A-operand DIRECT TO REGISTERS: a wave's A-rows are
//     wave-private, so LDS-staging them wastes LDS BW (the measured largest
//     pipe consumer: 38KB/wave/step of 256B/cyc). A-frags now load straight
//     from global (16B/lane, kk-halves share one 128B line); W keeps the
//     verified global_load_lds + XOR-swizzle path (W strips are shared by all
//     4 waves). LDS 40->24KB; everything else byte-identical to R10.
//     [Exhausted structural neighbors: R4 spill, R5 spill, R6 conflicts,
//      R7 occupancy, R8 L2 write-amp, R9 code bloat.]
//
// Pipeline (all on `stream`):
//   prep: convert GRU weights to bf16; combine biases; fold fusion weights
//   xprep: batch_features -> A1 (x0 bf16 [N,64]), A3 cols 0..63 (x1)
//   K1: h0_t0 = gru(x0, 0)            A1 -> A3 cols 64..319
//   K2: h1_t0 = gru(h0_t0, 0)         A3 -> A4 cols 256..511
//   K3: h0_t1 = gru(x1, h0_t0)        A3 -> A4 cols 0..255
//   coord: coord GRU -> A5 cols 256..287 (+ zero pad 288..319)
//   K4: h1_t1 = gru(h0_t1, h1_t0)     A4 -> A5 cols 0..255
//   K5: logits = mask * (relu([h1_t1|coord]@WF^T + BF) @ W2^T + b2)

#define NROWS 245760   // B*T = 8192*30
#define TT 30
#define KC 64

typedef __attribute__((ext_vector_type(4))) float f32x4;
typedef __attribute__((ext_vector_type(8))) short bf16x8;
typedef __attribute__((ext_vector_type(4))) unsigned short u16x4;

__device__ __forceinline__ float bf2f(unsigned short u) {
    union { unsigned int u; float f; } v; v.u = ((unsigned int)u) << 16; return v.f;
}
__device__ __forceinline__ unsigned short f2bf(float f) {
    union { float f; unsigned int u; } v; v.f = f;
    unsigned int u = v.u;
    unsigned int r = u + 0x7fffu + ((u >> 16) & 1u);   // RNE
    return (unsigned short)(r >> 16);
}
__device__ __forceinline__ float fexp2c(float x) {
    return __builtin_amdgcn_exp2f(fminf(x, 80.f));
}
__device__ __forceinline__ float fsigmoid(float x) {
    return __builtin_amdgcn_rcpf(1.f + fexp2c(-1.44269504f * x));
}
__device__ __forceinline__ float ftanh(float x) {
    float t = fexp2c(-2.88539008f * x);
    return (1.f - t) * __builtin_amdgcn_rcpf(1.f + t);
}
__device__ __forceinline__ f32x4 mfma16(bf16x8 a, bf16x8 b, f32x4 c) {
    return __builtin_amdgcn_mfma_f32_16x16x32_bf16(a, b, c, 0, 0, 0);
}
// async global->LDS, 16B/lane. LDS dest is wave-uniform base + lane*16 (linear);
// source address is per-lane (pre-swizzled by caller).
__device__ __forceinline__ void gload16(const unsigned short* g, unsigned short* l) {
    __builtin_amdgcn_global_load_lds(
        (const __attribute__((address_space(1))) void*)g,
        (__attribute__((address_space(3))) void*)l, 16, 0, 0);
}

// ---------------- prep kernels ----------------

__global__ void cvt_bf16(const float* __restrict__ src, unsigned short* __restrict__ dst, int n) {
    int i = blockIdx.x * 256 + threadIdx.x;
    if (i < n) dst[i] = f2bf(src[i]);
}

// three same-size (768x256) weight conversions in one launch
__global__ void cvt3_bf16(const float* __restrict__ s0, const float* __restrict__ s1,
                          const float* __restrict__ s2, unsigned short* __restrict__ d0,
                          unsigned short* __restrict__ d1, unsigned short* __restrict__ d2) {
    int i = blockIdx.x * 256 + threadIdx.x;   // 768*256 elements each
    d0[i] = f2bf(s0[i]);
    d1[i] = f2bf(s1[i]);
    d2[i] = f2bf(s2[i]);
}

// combined bias arrays [4][256]: br=bih_r+bhh_r, bz=bih_z+bhh_z, bin=bih_n, bhn=bhh_n
__global__ void bias_prep(const float* __restrict__ bih0, const float* __restrict__ bhh0, float* __restrict__ BC0,
                          const float* __restrict__ bih1, const float* __restrict__ bhh1, float* __restrict__ BC1) {
    int j = threadIdx.x;  // 256
    BC0[j]       = bih0[j]       + bhh0[j];
    BC0[256 + j] = bih0[256 + j] + bhh0[256 + j];
    BC0[512 + j] = bih0[512 + j];
    BC0[768 + j] = bhh0[512 + j];
    BC1[j]       = bih1[j]       + bhh1[j];
    BC1[256 + j] = bih1[256 + j] + bhh1[256 + j];
    BC1[512 + j] = bih1[512 + j];
    BC1[768 + j] = bhh1[512 + j];
}

// WF[o][k] (o<128, k<320): k<256 -> (W1a@We)[o][k]; 256<=k<288 -> (W1b@Wc)[o][k-256]; else 0
// BF[o] = b1[o] + W1a[o]·be + W1b[o]·bc
__global__ void fuse_prep(const float* __restrict__ We, const float* __restrict__ be,
                          const float* __restrict__ Wc, const float* __restrict__ bc_,
                          const float* __restrict__ W1, const float* __restrict__ b1,
                          unsigned short* __restrict__ WF, float* __restrict__ BF) {
    int idx = blockIdx.x * 256 + threadIdx.x;
    if (idx >= 128 * 320) return;
    int o = idx / 320, k = idx - o * 320;
    float v = 0.f;
    if (k < 256) {
        for (int i = 0; i < 128; ++i) v += W1[o * 256 + i] * We[i * 256 + k];
    } else if (k < 288) {
        int kk = k - 256;
        for (int i = 0; i < 128; ++i) v += W1[o * 256 + 128 + i] * Wc[i * 32 + kk];
    }
    WF[o * 320 + k] = f2bf(v);
    if (k == 0) {
        float s = b1[o];
        for (int i = 0; i < 128; ++i) s += W1[o * 256 + i] * be[i];
        for (int i = 0; i < 128; ++i) s += W1[o * 256 + 128 + i] * bc_[i];
        BF[o] = s;
    }
}

// batch_features [B,2,T,64] -> A1 (x0, [N,64] bf16), A3 cols 0..63 (x1, stride 320)
__global__ void xprep(const float* __restrict__ bf, unsigned short* __restrict__ A1,
                      unsigned short* __restrict__ A3) {
    int i = blockIdx.x * 256 + threadIdx.x;  // exactly N*16 threads
    int n = i >> 4, q = i & 15;              // 4 cols per thread
    int b = n / TT, t = n - b * TT;
    const float* p = bf + ((size_t)(b * 2) * TT + t) * 64 + q * 4;
    float4 v0 = *(const float4*)(p);
    float4 v1 = *(const float4*)(p + TT * 64);
    u16x4 o0 = { f2bf(v0.x), f2bf(v0.y), f2bf(v0.z), f2bf(v0.w) };
    u16x4 o1 = { f2bf(v1.x), f2bf(v1.y), f2bf(v1.z), f2bf(v1.w) };
    *(u16x4*)(A1 + (size_t)n * 64 + q * 4)  = o0;
    *(u16x4*)(A3 + (size_t)n * 320 + q * 4) = o1;
}

// coord GRU single step from h=0; writes A5 cols 256..287, zeros 288..319
__global__ void coord_gru(const float* __restrict__ coords, const float* __restrict__ WihC,
                          const float* __restrict__ bihC, const float* __restrict__ bhhC,
                          unsigned short* __restrict__ A5) {
    int n = blockIdx.x * 256 + threadIdx.x;
    if (n >= NROWS) return;
    const float4 c = *(const float4*)(coords + (size_t)n * 4);
    unsigned short* o = A5 + (size_t)n * 320 + 256;
    for (int j = 0; j < 32; ++j) {
        float gr = WihC[j * 4 + 0] * c.x + WihC[j * 4 + 1] * c.y + WihC[j * 4 + 2] * c.z + WihC[j * 4 + 3] * c.w + bihC[j];
        int j2 = 32 + j;
        float gz = WihC[j2 * 4 + 0] * c.x + WihC[j2 * 4 + 1] * c.y + WihC[j2 * 4 + 2] * c.z + WihC[j2 * 4 + 3] * c.w + bihC[j2];
        int j3 = 64 + j;
        float gn = WihC[j3 * 4 + 0] * c.x + WihC[j3 * 4 + 1] * c.y + WihC[j3 * 4 + 2] * c.z + WihC[j3 * 4 + 3] * c.w + bihC[j3];
        float r = fsigmoid(gr + bhhC[j]);
        float z = fsigmoid(gz + bhhC[j2]);
        float nn = ftanh(gn + r * bhhC[j3]);
        o[j] = f2bf((1.f - z) * nn);
    }
    for (int j = 32; j < 64; ++j) o[j] = 0;
}

// ---------------- GRU GEMM ----------------
// W LDS layout: row-major [192][64] bf16, granule g (16B) of row r stored at
// position g ^ (r&7). global_load_lds writes linearly; lane l's SOURCE granule
// is (l&7)^(l>>3)  [rule #21: linear dest + inverse-swizzled source].
// A-operand: DIRECT from global per lane — lane l of wave w holds
// A[row0 + w*32 + {0,16} + (l&15)][kc + kk*32 + (l>>4)*8 ..+8] (16B load).
// The kk=0/1 halves of a row share one aligned 128B line (aoff,kc mult. of 64).
__device__ __forceinline__ void gemm_phase(
    const unsigned short* __restrict__ Ag, int lda, int aoff, int Kp,
    const unsigned short* __restrict__ Wg,
    unsigned short* sW,
    int row0, int cb, int tid,
    f32x4 (&aR)[2][4], f32x4 (&aZ)[2][4], f32x4 (&aG)[2][4]) {
    const int lane = tid & 63, wave = tid >> 6;
    const int lr = lane & 15, lk = lane >> 4;
    const int xr = (lr & 7) * 8;
    const int gsrc = ((lane & 7) ^ (lane >> 3)) * 8;  // W source element offset within row
    const int lrow = lane >> 3;                        // row within 8-row group
    // per-lane direct-A bases (wave-private rows; no LDS round-trip)
    const unsigned short* a0p = Ag + (size_t)(row0 + wave * 32 + lr) * lda + aoff + lk * 8;
    const unsigned short* a1p = a0p + (size_t)16 * lda;
    for (int kc = 0; kc < Kp; kc += KC) {
        __syncthreads();
        // stage W: 192 rows (12 strips x 16) = 24 groups; 6 gloads/wave
#pragma unroll
        for (int it = 0; it < 6; ++it) {
            int gw = it * 4 + wave;
            int t = gw >> 1;                      // strip index 0..11
            int c = (gw & 1) * 8 + lrow;          // row within strip
            int grow = (t >> 2) * 256 + cb * 64 + (t & 3) * 16 + c;
            const unsigned short* src = Wg + (size_t)grow * Kp + kc + gsrc;
            gload16(src, sW + gw * 512);
        }
        // direct A fragment loads (latency drains with W at the barrier)
        bf16x8 a0[2], a1[2];
        a0[0] = *(const bf16x8*)(a0p + kc);
        a0[1] = *(const bf16x8*)(a0p + kc + 32);
        a1[0] = *(const bf16x8*)(a1p + kc);
        a1[1] = *(const bf16x8*)(a1p + kc + 32);
        __syncthreads();
#pragma unroll
        for (int kk = 0; kk < 2; ++kk) {
            int kx = (kk * 32 + lk * 8) ^ xr;
#pragma unroll
            for (int t = 0; t < 12; ++t) {
                bf16x8 b = *(const bf16x8*)(sW + (t * 16 + lr) * KC + kx);
                int gi = t & 3;
                if (t < 4) {
                    aR[0][gi] = mfma16(a0[kk], b, aR[0][gi]);
                    aR[1][gi] = mfma16(a1[kk], b, aR[1][gi]);
                } else if (t < 8) {
                    aZ[0][gi] = mfma16(a0[kk], b, aZ[0][gi]);
                    aZ[1][gi] = mfma16(a1[kk], b, aZ[1][gi]);
                } else {
                    aG[0][gi] = mfma16(a0[kk], b, aG[0][gi]);
                    aG[1][gi] = mfma16(a1[kk], b, aG[1][gi]);
                }
            }
        }
    }
}

// block: 128 rows x 64 h-cols. 1D grid NROWS/128*4, XCD-swizzled; cb = low 2 bits.
template <bool HAS_HH, bool HAS_HPREV>
__global__ __launch_bounds__(256, 3) void gru_gemm(
    const unsigned short* __restrict__ A, int lda,
    int Kih, const unsigned short* __restrict__ Wih,
    int Khh, const unsigned short* __restrict__ Whh,
    const float* __restrict__ bc,
    const unsigned short* __restrict__ hprev, int ldh,
    unsigned short* __restrict__ dst, int ldd) {
    __shared__ unsigned short sW[192 * KC];
    const int tid = threadIdx.x;
    // XCD-bijective swizzle: nwg % 8 == 0, so chunked form is exact.
    const int nwg = gridDim.x;
    const int wgid = (blockIdx.x & 7) * (nwg >> 3) + (blockIdx.x >> 3);
    const int cb = wgid & 3;
    const int row0 = (wgid >> 2) * 128;
    f32x4 aR[2][4] = {}, aZ[2][4] = {}, aIN[2][4] = {}, aHN[2][4] = {};
    gemm_phase(A, lda, 0, Kih, Wih, sW, row0, cb, tid, aR, aZ, aIN);
    if (HAS_HH)
        gemm_phase(A, lda, Kih, Khh, Whh, sW, row0, cb, tid, aR, aZ, aHN);
    // epilogue: gates
    const int lane = tid & 63, wave = tid >> 6;
    const int lr = lane & 15, lk = lane >> 4;
    const int jc = cb * 64;
    const int rb = row0 + wave * 32;
#pragma unroll
    for (int s = 0; s < 2; ++s) {
#pragma unroll
        for (int gi = 0; gi < 4; ++gi) {
            int j = jc + gi * 16 + lr;
            float br = bc[j], bz = bc[256 + j], bin = bc[512 + j], bhn = bc[768 + j];
#pragma unroll
            for (int q = 0; q < 4; ++q) {
                int row = rb + s * 16 + lk * 4 + q;
                float rg = fsigmoid(aR[s][gi][q] + br);
                float zg = fsigmoid(aZ[s][gi][q] + bz);
                float hn = HAS_HH ? aHN[s][gi][q] : 0.f;
                float ng = ftanh(aIN[s][gi][q] + bin + rg * (hn + bhn));
                float h = (1.f - zg) * ng;
                if (HAS_HPREV) h += zg * bf2f(hprev[(size_t)row * ldh + j]);
                dst[(size_t)row * ldd + j] = f2bf(h);
            }
        }
    }
}

// fusion + logits: hid = relu(A5 @ WF^T + BF); out = mask * (hid @ W2^T + b2)
__global__ __launch_bounds__(256, 3) void fusion_logits(
    const unsigned short* __restrict__ A,   // [N][320]
    const unsigned short* __restrict__ WF,  // [128][320]
    const float* __restrict__ BF, const float* __restrict__ W2, const float* __restrict__ b2,
    const int* __restrict__ mask, float* __restrict__ out) {
    __shared__ unsigned short sA[64 * KC];
    __shared__ unsigned short sW[128 * KC];
    const int tid = threadIdx.x, lane = tid & 63, wave = tid >> 6;
    const int lr = lane & 15, lk = lane >> 4;
    const int xr = (lr & 7) * 8;
    const int gsrc = ((lane & 7) ^ (lane >> 3)) * 8;
    const int lrow = lane >> 3;
    const int row0 = blockIdx.x * 64;
    f32x4 acc[8] = {};
    for (int kc = 0; kc < 320; kc += KC) {
        __syncthreads();
#pragma unroll
        for (int it = 0; it < 2; ++it) {
            int grp = it * 4 + wave;   // 8 groups = 64 rows
            const unsigned short* src = A + (size_t)(row0 + grp * 8 + lrow) * 320 + kc + gsrc;
            gload16(src, sA + grp * 512);
        }
#pragma unroll
        for (int it = 0; it < 4; ++it) {
            int gw = it * 4 + wave;    // 16 groups = 128 rows
            const unsigned short* src = WF + (size_t)(gw * 8 + lrow) * 320 + kc + gsrc;
            gload16(src, sW + gw * 512);
        }
        __syncthreads();
#pragma unroll
        for (int kk = 0; kk < 2; ++kk) {
            int kx = (kk * 32 + lk * 8) ^ xr;
            bf16x8 a = *(const bf16x8*)(sA + (wave * 16 + lr) * KC + kx);
#pragma unroll
            for (int t = 0; t < 8; ++t) {
                bf16x8 b = *(const bf16x8*)(sW + (t * 16 + lr) * KC + kx);
                acc[t] = mfma16(a, b, acc[t]);
            }
        }
    }
#pragma unroll
    for (int q = 0; q < 4; ++q) {
        float l0 = 0.f, l1 = 0.f;
#pragma unroll
        for (int t = 0; t < 8; ++t) {
            int j = t * 16 + lr;
            float h = acc[t][q] + BF[j];
            h = h > 0.f ? h : 0.f;
            l0 += h * W2[j];
            l1 += h * W2[128 + j];
        }
#pragma unroll
        for (int m = 1; m < 16; m <<= 1) {
            l0 += __shfl_xor(l0, m, 64);
            l1 += __shfl_xor(l1, m, 64);
        }
        if (lr == 0) {
            int row = row0 + wave * 16 + lk * 4 + q;
            float v0 = l0 + b2[0], v1 = l1 + b2[1];
            if (!mask[row]) { v0 = 0.f; v1 = 0.f; }  // valid_mask is int32 on device
            out[(size_t)row * 2]     = v0;
            out[(size_t)row * 2 + 1] = v1;
        }
    }
}

// ---------------- launch ----------------

extern "C" void kernel_launch(void* const* d_in, const int* in_sizes, int n_in,
                              void* d_out, int out_size, void* d_ws, size_t ws_size,
                              hipStream_t stream) {
    const float* bfeat  = (const float*)d_in[0];
    const float* coords = (const float*)d_in[1];
    const int* mask = (const int*)d_in[2];  // jnp bool -> int32 on device
    const float* Wih0 = (const float*)d_in[3];
    const float* Whh0 = (const float*)d_in[4];
    const float* bih0 = (const float*)d_in[5];
    const float* bhh0 = (const float*)d_in[6];
    const float* Wih1 = (const float*)d_in[7];
    const float* Whh1 = (const float*)d_in[8];
    const float* bih1 = (const float*)d_in[9];
    const float* bhh1 = (const float*)d_in[10];
    const float* WihC = (const float*)d_in[11];
    // d_in[12] = WhhC: unused (coord GRU starts from h=0)
    const float* bihC = (const float*)d_in[13];
    const float* bhhC = (const float*)d_in[14];
    const float* We = (const float*)d_in[15];
    const float* be = (const float*)d_in[16];
    const float* Wc = (const float*)d_in[17];
    const float* bc_ = (const float*)d_in[18];
    const float* W1 = (const float*)d_in[19];
    const float* b1 = (const float*)d_in[20];
    const float* W2 = (const float*)d_in[21];
    const float* b2 = (const float*)d_in[22];
    float* out = (float*)d_out;

    const size_t N = NROWS;
    char* ws = (char*)d_ws;
    unsigned short* A4 = (unsigned short*)ws;                       // [N,512]
    unsigned short* A1 = (unsigned short*)ws;                       // [N,64]  (aliases A4; dead before K2)
    unsigned short* A3 = (unsigned short*)(ws + N * 512 * 2);       // [N,320]
    unsigned short* A5 = A3;                                        // [N,320] (aliases A3; A3 dead after K3)
    char* wp = ws + N * 512 * 2 + N * 320 * 2;
    unsigned short* WB0  = (unsigned short*)wp; wp += 768 * 64 * 2;
    unsigned short* WBh0 = (unsigned short*)wp; wp += 768 * 256 * 2;
    unsigned short* WB1  = (unsigned short*)wp; wp += 768 * 256 * 2;
    unsigned short* WBh1 = (unsigned short*)wp; wp += 768 * 256 * 2;
    unsigned short* WF   = (unsigned short*)wp; wp += 128 * 320 * 2;
    float* BC0 = (float*)wp; wp += 1024 * 4;
    float* BC1 = (float*)wp; wp += 1024 * 4;
    float* BF  = (float*)wp; wp += 128 * 4;

    // prep
    cvt_bf16<<<192, 256, 0, stream>>>(Wih0, WB0, 768 * 64);
    cvt3_bf16<<<768, 256, 0, stream>>>(Whh0, Wih1, Whh1, WBh0, WB1, WBh1);
    bias_prep<<<1, 256, 0, stream>>>(bih0, bhh0, BC0, bih1, bhh1, BC1);
    fuse_prep<<<160, 256, 0, stream>>>(We, be, Wc, bc_, W1, b1, WF, BF);
    xprep<<<15360, 256, 0, stream>>>(bfeat, A1, A3);

    const int gg = (NROWS / 128) * 4;  // 7680, % 8 == 0
    // K1: h0_t0 (x0, no hh, no hprev)
    gru_gemm<false, false><<<gg, 256, 0, stream>>>(A1, 64, 64, WB0, 0, nullptr, BC0, nullptr, 0, A3 + 64, 320);
    // K2: h1_t0 (h0_t0, no hh, no hprev)
    gru_gemm<false, false><<<gg, 256, 0, stream>>>(A3 + 64, 320, 256, WB1, 0, nullptr, BC1, nullptr, 0, A4 + 256, 512);
    // K3: h0_t1 (x1 + h0_t0)
    gru_gemm<true, true><<<gg, 256, 0, stream>>>(A3, 320, 64, WB0, 256, WBh0, BC0, A3 + 64, 320, A4, 512);
    // coord GRU -> A5 cols 256..319 (must run after K3: A5 aliases A3)
    coord_gru<<<NROWS / 256, 256, 0, stream>>>(coords, WihC, bihC, bhhC, A5);
    // K4: h1_t1 (h0_t1 + h1_t0) -> A5 cols 0..255
    gru_gemm<true, true><<<gg, 256, 0, stream>>>(A4, 512, 256, WB1, 256, WBh1, BC1, A4 + 256, 512, A5, 320);
    // K5: fusion + logits
    fusion_logits<<<NROWS / 64, 256, 0, stream>>>(A5, WF, BF, W2, b2, mask, out);

    (void)in_sizes; (void)n_in; (void)out_size; (void)ws_size;
}

// Round 12
// 783.463 us; speedup vs baseline: 1.0421x; 1.0421x over previous
//
#include <hip/hip_runtime.h>

// EventADModel: 2-frame 2-layer event GRU (H=256) + coord GRU (H=32, 1 step from 0)
// + fused linear fusion head, all via bf16 MFMA GEMMs with fused gate epilogues.
//
// R12: restore best-measured configuration (R10, 784us). Structure: 16x16x32
//     single-buffer 2-barrier GEMM, runtime shape args, launch_bounds(256,3),
//     XCD-swizzled 1D grid, global_load_lds staging with inverse-swizzled
//     source + XOR-swizzled LDS reads (0 bank conflicts).
//     Exhausted neighbors (all regressed, mechanisms diagnosed): R4 dbuf+hoist
//     (spill), R5 occ=4 (spill), R6 32x32 (bank conflicts), R7 lean dbuf
//     (lost 3rd resident block), R8 2x2 decomp (L2 write amp), R9 template
//     unroll (code bloat), R11 direct-reg A (coalescing loss on the drain path).
//     Binding constraint: 4 accumulator sets (128 AGPR) -> 3 waves/SIMD ->
//     single-buffer LDS -> 2-barrier drain loop; implicit 3-block overlap
//     already captures pipelining gains (m114). ~575 TF effective = ceiling.
//
// Pipeline (all on `stream`):
//   prep: convert GRU weights to bf16; combine biases; fold fusion weights
//   xprep: batch_features -> A1 (x0 bf16 [N,64]), A3 cols 0..63 (x1)
//   K1: h0_t0 = gru(x0, 0)            A1 -> A3 cols 64..319
//   K2: h1_t0 = gru(h0_t0, 0)         A3 -> A4 cols 256..511
//   K3: h0_t1 = gru(x1, h0_t0)        A3 -> A4 cols 0..255
//   coord: coord GRU -> A5 cols 256..287 (+ zero pad 288..319)
//   K4: h1_t1 = gru(h0_t1, h1_t0)     A4 -> A5 cols 0..255
//   K5: logits = mask * (relu([h1_t1|coord]@WF^T + BF) @ W2^T + b2)

#define NROWS 245760   // B*T = 8192*30
#define TT 30
#define KC 64

typedef __attribute__((ext_vector_type(4))) float f32x4;
typedef __attribute__((ext_vector_type(8))) short bf16x8;
typedef __attribute__((ext_vector_type(4))) unsigned short u16x4;

__device__ __forceinline__ float bf2f(unsigned short u) {
    union { unsigned int u; float f; } v; v.u = ((unsigned int)u) << 16; return v.f;
}
__device__ __forceinline__ unsigned short f2bf(float f) {
    union { float f; unsigned int u; } v; v.f = f;
    unsigned int u = v.u;
    unsigned int r = u + 0x7fffu + ((u >> 16) & 1u);   // RNE
    return (unsigned short)(r >> 16);
}
__device__ __forceinline__ float fexp2c(float x) {
    return __builtin_amdgcn_exp2f(fminf(x, 80.f));
}
__device__ __forceinline__ float fsigmoid(float x) {
    return __builtin_amdgcn_rcpf(1.f + fexp2c(-1.44269504f * x));
}
__device__ __forceinline__ float ftanh(float x) {
    float t = fexp2c(-2.88539008f * x);
    return (1.f - t) * __builtin_amdgcn_rcpf(1.f + t);
}
__device__ __forceinline__ f32x4 mfma16(bf16x8 a, bf16x8 b, f32x4 c) {
    return __builtin_amdgcn_mfma_f32_16x16x32_bf16(a, b, c, 0, 0, 0);
}
// async global->LDS, 16B/lane. LDS dest is wave-uniform base + lane*16 (linear);
// source address is per-lane (pre-swizzled by caller).
__device__ __forceinline__ void gload16(const unsigned short* g, unsigned short* l) {
    __builtin_amdgcn_global_load_lds(
        (const __attribute__((address_space(1))) void*)g,
        (__attribute__((address_space(3))) void*)l, 16, 0, 0);
}

// ---------------- prep kernels ----------------

__global__ void cvt_bf16(const float* __restrict__ src, unsigned short* __restrict__ dst, int n) {
    int i = blockIdx.x * 256 + threadIdx.x;
    if (i < n) dst[i] = f2bf(src[i]);
}

// three same-size (768x256) weight conversions in one launch
__global__ void cvt3_bf16(const float* __restrict__ s0, const float* __restrict__ s1,
                          const float* __restrict__ s2, unsigned short* __restrict__ d0,
                          unsigned short* __restrict__ d1, unsigned short* __restrict__ d2) {
    int i = blockIdx.x * 256 + threadIdx.x;   // 768*256 elements each
    d0[i] = f2bf(s0[i]);
    d1[i] = f2bf(s1[i]);
    d2[i] = f2bf(s2[i]);
}

// combined bias arrays [4][256]: br=bih_r+bhh_r, bz=bih_z+bhh_z, bin=bih_n, bhn=bhh_n
__global__ void bias_prep(const float* __restrict__ bih0, const float* __restrict__ bhh0, float* __restrict__ BC0,
                          const float* __restrict__ bih1, const float* __restrict__ bhh1, float* __restrict__ BC1) {
    int j = threadIdx.x;  // 256
    BC0[j]       = bih0[j]       + bhh0[j];
    BC0[256 + j] = bih0[256 + j] + bhh0[256 + j];
    BC0[512 + j] = bih0[512 + j];
    BC0[768 + j] = bhh0[512 + j];
    BC1[j]       = bih1[j]       + bhh1[j];
    BC1[256 + j] = bih1[256 + j] + bhh1[256 + j];
    BC1[512 + j] = bih1[512 + j];
    BC1[768 + j] = bhh1[512 + j];
}

// WF[o][k] (o<128, k<320): k<256 -> (W1a@We)[o][k]; 256<=k<288 -> (W1b@Wc)[o][k-256]; else 0
// BF[o] = b1[o] + W1a[o]·be + W1b[o]·bc
__global__ void fuse_prep(const float* __restrict__ We, const float* __restrict__ be,
                          const float* __restrict__ Wc, const float* __restrict__ bc_,
                          const float* __restrict__ W1, const float* __restrict__ b1,
                          unsigned short* __restrict__ WF, float* __restrict__ BF) {
    int idx = blockIdx.x * 256 + threadIdx.x;
    if (idx >= 128 * 320) return;
    int o = idx / 320, k = idx - o * 320;
    float v = 0.f;
    if (k < 256) {
        for (int i = 0; i < 128; ++i) v += W1[o * 256 + i] * We[i * 256 + k];
    } else if (k < 288) {
        int kk = k - 256;
        for (int i = 0; i < 128; ++i) v += W1[o * 256 + 128 + i] * Wc[i * 32 + kk];
    }
    WF[o * 320 + k] = f2bf(v);
    if (k == 0) {
        float s = b1[o];
        for (int i = 0; i < 128; ++i) s += W1[o * 256 + i] * be[i];
        for (int i = 0; i < 128; ++i) s += W1[o * 256 + 128 + i] * bc_[i];
        BF[o] = s;
    }
}

// batch_features [B,2,T,64] -> A1 (x0, [N,64] bf16), A3 cols 0..63 (x1, stride 320)
__global__ void xprep(const float* __restrict__ bf, unsigned short* __restrict__ A1,
                      unsigned short* __restrict__ A3) {
    int i = blockIdx.x * 256 + threadIdx.x;  // exactly N*16 threads
    int n = i >> 4, q = i & 15;              // 4 cols per thread
    int b = n / TT, t = n - b * TT;
    const float* p = bf + ((size_t)(b * 2) * TT + t) * 64 + q * 4;
    float4 v0 = *(const float4*)(p);
    float4 v1 = *(const float4*)(p + TT * 64);
    u16x4 o0 = { f2bf(v0.x), f2bf(v0.y), f2bf(v0.z), f2bf(v0.w) };
    u16x4 o1 = { f2bf(v1.x), f2bf(v1.y), f2bf(v1.z), f2bf(v1.w) };
    *(u16x4*)(A1 + (size_t)n * 64 + q * 4)  = o0;
    *(u16x4*)(A3 + (size_t)n * 320 + q * 4) = o1;
}

// coord GRU single step from h=0; writes A5 cols 256..287, zeros 288..319
__global__ void coord_gru(const float* __restrict__ coords, const float* __restrict__ WihC,
                          const float* __restrict__ bihC, const float* __restrict__ bhhC,
                          unsigned short* __restrict__ A5) {
    int n = blockIdx.x * 256 + threadIdx.x;
    if (n >= NROWS) return;
    const float4 c = *(const float4*)(coords + (size_t)n * 4);
    unsigned short* o = A5 + (size_t)n * 320 + 256;
    for (int j = 0; j < 32; ++j) {
        float gr = WihC[j * 4 + 0] * c.x + WihC[j * 4 + 1] * c.y + WihC[j * 4 + 2] * c.z + WihC[j * 4 + 3] * c.w + bihC[j];
        int j2 = 32 + j;
        float gz = WihC[j2 * 4 + 0] * c.x + WihC[j2 * 4 + 1] * c.y + WihC[j2 * 4 + 2] * c.z + WihC[j2 * 4 + 3] * c.w + bihC[j2];
        int j3 = 64 + j;
        float gn = WihC[j3 * 4 + 0] * c.x + WihC[j3 * 4 + 1] * c.y + WihC[j3 * 4 + 2] * c.z + WihC[j3 * 4 + 3] * c.w + bihC[j3];
        float r = fsigmoid(gr + bhhC[j]);
        float z = fsigmoid(gz + bhhC[j2]);
        float nn = ftanh(gn + r * bhhC[j3]);
        o[j] = f2bf((1.f - z) * nn);
    }
    for (int j = 32; j < 64; ++j) o[j] = 0;
}

// ---------------- GRU GEMM ----------------
// LDS layout (both A and W): row-major [rows][64] bf16, granule g (16B) of row r
// stored at position g ^ (r&7). global_load_lds writes linearly (one wave insn =
// 8 LDS rows); lane l holds dest (row=base+(l>>3), pos=l&7) so its SOURCE granule
// is (l&7)^(l>>3)  [rule #21: linear dest + inverse-swizzled source + swizzled read].
__device__ __forceinline__ void gemm_phase(
    const unsigned short* __restrict__ Ag, int lda, int aoff, int Kp,
    const unsigned short* __restrict__ Wg,
    unsigned short* sA, unsigned short* sW,
    int row0, int cb, int tid,
    f32x4 (&aR)[2][4], f32x4 (&aZ)[2][4], f32x4 (&aG)[2][4]) {
    const int lane = tid & 63, wave = tid >> 6;
    const int lr = lane & 15, lk = lane >> 4;
    const int xr = (lr & 7) * 8;
    const int gsrc = ((lane & 7) ^ (lane >> 3)) * 8;  // source element offset within row
    const int lrow = lane >> 3;                        // row within 8-row group
    for (int kc = 0; kc < Kp; kc += KC) {
        __syncthreads();
        // stage A: 128 rows = 16 groups of 8 rows; 4 gloads/wave
#pragma unroll
        for (int it = 0; it < 4; ++it) {
            int grp = it * 4 + wave;
            const unsigned short* src = Ag + (size_t)(row0 + grp * 8 + lrow) * lda + aoff + kc + gsrc;
            gload16(src, sA + grp * 512);
        }
        // stage W: 192 rows (12 strips x 16) = 24 groups; 6 gloads/wave
#pragma unroll
        for (int it = 0; it < 6; ++it) {
            int gw = it * 4 + wave;
            int t = gw >> 1;                      // strip index 0..11
            int c = (gw & 1) * 8 + lrow;          // row within strip
            int grow = (t >> 2) * 256 + cb * 64 + (t & 3) * 16 + c;
            const unsigned short* src = Wg + (size_t)grow * Kp + kc + gsrc;
            gload16(src, sW + gw * 512);
        }
        __syncthreads();
#pragma unroll
        for (int kk = 0; kk < 2; ++kk) {
            int kx = (kk * 32 + lk * 8) ^ xr;
            bf16x8 a0 = *(const bf16x8*)(sA + (wave * 32 + lr) * KC + kx);
            bf16x8 a1 = *(const bf16x8*)(sA + (wave * 32 + 16 + lr) * KC + kx);
#pragma unroll
            for (int t = 0; t < 12; ++t) {
                bf16x8 b = *(const bf16x8*)(sW + (t * 16 + lr) * KC + kx);
                int gi = t & 3;
                if (t < 4) {
                    aR[0][gi] = mfma16(a0, b, aR[0][gi]);
                    aR[1][gi] = mfma16(a1, b, aR[1][gi]);
                } else if (t < 8) {
                    aZ[0][gi] = mfma16(a0, b, aZ[0][gi]);
                    aZ[1][gi] = mfma16(a1, b, aZ[1][gi]);
                } else {
                    aG[0][gi] = mfma16(a0, b, aG[0][gi]);
                    aG[1][gi] = mfma16(a1, b, aG[1][gi]);
                }
            }
        }
    }
}

// block: 128 rows x 64 h-cols. 1D grid NROWS/128*4, XCD-swizzled; cb = low 2 bits.
template <bool HAS_HH, bool HAS_HPREV>
__global__ __launch_bounds__(256, 3) void gru_gemm(
    const unsigned short* __restrict__ A, int lda,
    int Kih, const unsigned short* __restrict__ Wih,
    int Khh, const unsigned short* __restrict__ Whh,
    const float* __restrict__ bc,
    const unsigned short* __restrict__ hprev, int ldh,
    unsigned short* __restrict__ dst, int ldd) {
    __shared__ unsigned short sA[128 * KC];
    __shared__ unsigned short sW[192 * KC];
    const int tid = threadIdx.x;
    // XCD-bijective swizzle: nwg % 8 == 0, so chunked form is exact.
    const int nwg = gridDim.x;
    const int wgid = (blockIdx.x & 7) * (nwg >> 3) + (blockIdx.x >> 3);
    const int cb = wgid & 3;
    const int row0 = (wgid >> 2) * 128;
    f32x4 aR[2][4] = {}, aZ[2][4] = {}, aIN[2][4] = {}, aHN[2][4] = {};
    gemm_phase(A, lda, 0, Kih, Wih, sA, sW, row0, cb, tid, aR, aZ, aIN);
    if (HAS_HH)
        gemm_phase(A, lda, Kih, Khh, Whh, sA, sW, row0, cb, tid, aR, aZ, aHN);
    // epilogue: gates
    const int lane = tid & 63, wave = tid >> 6;
    const int lr = lane & 15, lk = lane >> 4;
    const int jc = cb * 64;
    const int rb = row0 + wave * 32;
#pragma unroll
    for (int s = 0; s < 2; ++s) {
#pragma unroll
        for (int gi = 0; gi < 4; ++gi) {
            int j = jc + gi * 16 + lr;
            float br = bc[j], bz = bc[256 + j], bin = bc[512 + j], bhn = bc[768 + j];
#pragma unroll
            for (int q = 0; q < 4; ++q) {
                int row = rb + s * 16 + lk * 4 + q;
                float rg = fsigmoid(aR[s][gi][q] + br);
                float zg = fsigmoid(aZ[s][gi][q] + bz);
                float hn = HAS_HH ? aHN[s][gi][q] : 0.f;
                float ng = ftanh(aIN[s][gi][q] + bin + rg * (hn + bhn));
                float h = (1.f - zg) * ng;
                if (HAS_HPREV) h += zg * bf2f(hprev[(size_t)row * ldh + j]);
                dst[(size_t)row * ldd + j] = f2bf(h);
            }
        }
    }
}

// fusion + logits: hid = relu(A5 @ WF^T + BF); out = mask * (hid @ W2^T + b2)
__global__ __launch_bounds__(256, 3) void fusion_logits(
    const unsigned short* __restrict__ A,   // [N][320]
    const unsigned short* __restrict__ WF,  // [128][320]
    const float* __restrict__ BF, const float* __restrict__ W2, const float* __restrict__ b2,
    const int* __restrict__ mask, float* __restrict__ out) {
    __shared__ unsigned short sA[64 * KC];
    __shared__ unsigned short sW[128 * KC];
    const int tid = threadIdx.x, lane = tid & 63, wave = tid >> 6;
    const int lr = lane & 15, lk = lane >> 4;
    const int xr = (lr & 7) * 8;
    const int gsrc = ((lane & 7) ^ (lane >> 3)) * 8;
    const int lrow = lane >> 3;
    const int row0 = blockIdx.x * 64;
    f32x4 acc[8] = {};
    for (int kc = 0; kc < 320; kc += KC) {
        __syncthreads();
#pragma unroll
        for (int it = 0; it < 2; ++it) {
            int grp = it * 4 + wave;   // 8 groups = 64 rows
            const unsigned short* src = A + (size_t)(row0 + grp * 8 + lrow) * 320 + kc + gsrc;
            gload16(src, sA + grp * 512);
        }
#pragma unroll
        for (int it = 0; it < 4; ++it) {
            int gw = it * 4 + wave;    // 16 groups = 128 rows
            const unsigned short* src = WF + (size_t)(gw * 8 + lrow) * 320 + kc + gsrc;
            gload16(src, sW + gw * 512);
        }
        __syncthreads();
#pragma unroll
        for (int kk = 0; kk < 2; ++kk) {
            int kx = (kk * 32 + lk * 8) ^ xr;
            bf16x8 a = *(const bf16x8*)(sA + (wave * 16 + lr) * KC + kx);
#pragma unroll
            for (int t = 0; t < 8; ++t) {
                bf16x8 b = *(const bf16x8*)(sW + (t * 16 + lr) * KC + kx);
                acc[t] = mfma16(a, b, acc[t]);
            }
        }
    }
#pragma unroll
    for (int q = 0; q < 4; ++q) {
        float l0 = 0.f, l1 = 0.f;
#pragma unroll
        for (int t = 0; t < 8; ++t) {
            int j = t * 16 + lr;
            float h = acc[t][q] + BF[j];
            h = h > 0.f ? h : 0.f;
            l0 += h * W2[j];
            l1 += h * W2[128 + j];
        }
#pragma unroll
        for (int m = 1; m < 16; m <<= 1) {
            l0 += __shfl_xor(l0, m, 64);
            l1 += __shfl_xor(l1, m, 64);
        }
        if (lr == 0) {
            int row = row0 + wave * 16 + lk * 4 + q;
            float v0 = l0 + b2[0], v1 = l1 + b2[1];
            if (!mask[row]) { v0 = 0.f; v1 = 0.f; }  // valid_mask is int32 on device
            out[(size_t)row * 2]     = v0;
            out[(size_t)row * 2 + 1] = v1;
        }
    }
}

// ---------------- launch ----------------

extern "C" void kernel_launch(void* const* d_in, const int* in_sizes, int n_in,
                              void* d_out, int out_size, void* d_ws, size_t ws_size,
                              hipStream_t stream) {
    const float* bfeat  = (const float*)d_in[0];
    const float* coords = (const float*)d_in[1];
    const int* mask = (const int*)d_in[2];  // jnp bool -> int32 on device
    const float* Wih0 = (const float*)d_in[3];
    const float* Whh0 = (const float*)d_in[4];
    const float* bih0 = (const float*)d_in[5];
    const float* bhh0 = (const float*)d_in[6];
    const float* Wih1 = (const float*)d_in[7];
    const float* Whh1 = (const float*)d_in[8];
    const float* bih1 = (const float*)d_in[9];
    const float* bhh1 = (const float*)d_in[10];
    const float* WihC = (const float*)d_in[11];
    // d_in[12] = WhhC: unused (coord GRU starts from h=0)
    const float* bihC = (const float*)d_in[13];
    const float* bhhC = (const float*)d_in[14];
    const float* We = (const float*)d_in[15];
    const float* be = (const float*)d_in[16];
    const float* Wc = (const float*)d_in[17];
    const float* bc_ = (const float*)d_in[18];
    const float* W1 = (const float*)d_in[19];
    const float* b1 = (const float*)d_in[20];
    const float* W2 = (const float*)d_in[21];
    const float* b2 = (const float*)d_in[22];
    float* out = (float*)d_out;

    const size_t N = NROWS;
    char* ws = (char*)d_ws;
    unsigned short* A4 = (unsigned short*)ws;                       // [N,512]
    unsigned short* A1 = (unsigned short*)ws;                       // [N,64]  (aliases A4; dead before K2)
    unsigned short* A3 = (unsigned short*)(ws + N * 512 * 2);       // [N,320]
    unsigned short* A5 = A3;                                        // [N,320] (aliases A3; A3 dead after K3)
    char* wp = ws + N * 512 * 2 + N * 320 * 2;
    unsigned short* WB0  = (unsigned short*)wp; wp += 768 * 64 * 2;
    unsigned short* WBh0 = (unsigned short*)wp; wp += 768 * 256 * 2;
    unsigned short* WB1  = (unsigned short*)wp; wp += 768 * 256 * 2;
    unsigned short* WBh1 = (unsigned short*)wp; wp += 768 * 256 * 2;
    unsigned short* WF   = (unsigned short*)wp; wp += 128 * 320 * 2;
    float* BC0 = (float*)wp; wp += 1024 * 4;
    float* BC1 = (float*)wp; wp += 1024 * 4;
    float* BF  = (float*)wp; wp += 128 * 4;

    // prep
    cvt_bf16<<<192, 256, 0, stream>>>(Wih0, WB0, 768 * 64);
    cvt3_bf16<<<768, 256, 0, stream>>>(Whh0, Wih1, Whh1, WBh0, WB1, WBh1);
    bias_prep<<<1, 256, 0, stream>>>(bih0, bhh0, BC0, bih1, bhh1, BC1);
    fuse_prep<<<160, 256, 0, stream>>>(We, be, Wc, bc_, W1, b1, WF, BF);
    xprep<<<15360, 256, 0, stream>>>(bfeat, A1, A3);

    const int gg = (NROWS / 128) * 4;  // 7680, % 8 == 0
    // K1: h0_t0 (x0, no hh, no hprev)
    gru_gemm<false, false><<<gg, 256, 0, stream>>>(A1, 64, 64, WB0, 0, nullptr, BC0, nullptr, 0, A3 + 64, 320);
    // K2: h1_t0 (h0_t0, no hh, no hprev)
    gru_gemm<false, false><<<gg, 256, 0, stream>>>(A3 + 64, 320, 256, WB1, 0, nullptr, BC1, nullptr, 0, A4 + 256, 512);
    // K3: h0_t1 (x1 + h0_t0)
    gru_gemm<true, true><<<gg, 256, 0, stream>>>(A3, 320, 64, WB0, 256, WBh0, BC0, A3 + 64, 320, A4, 512);
    // coord GRU -> A5 cols 256..319 (must run after K3: A5 aliases A3)
    coord_gru<<<NROWS / 256, 256, 0, stream>>>(coords, WihC, bihC, bhhC, A5);
    // K4: h1_t1 (h0_t1 + h1_t0) -> A5 cols 0..255
    gru_gemm<true, true><<<gg, 256, 0, stream>>>(A4, 512, 256, WB1, 256, WBh1, BC1, A4 + 256, 512, A5, 320);
    // K5: fusion + logits
    fusion_logits<<<NROWS / 64, 256, 0, stream>>>(A5, WF, BF, W2, b2, mask, out);

    (void)in_sizes; (void)n_in; (void)out_size; (void)ws_size;
}